// Round 6
// baseline (63.787 us; speedup 1.0000x reference)
//
#include <hip/hip_runtime.h>

namespace {

constexpr int G    = 76;
constexpr int NA   = 3;
constexpr int NC   = 85;             // 5 + 80 channels per anchor
constexpr int GG   = G * G;          // 5776
constexpr int NPT  = 16 * NA * GG;   // 277,248 output points
constexpr int NT   = 256;
constexpr int NBLK = NPT / NT;       // 1083 (exact)

__device__ __forceinline__ float sigmoidf(float v) {
    return __builtin_amdgcn_rcpf(1.0f + __expf(-v));
}

__global__ __launch_bounds__(NT)
void yolo_decode(const float* __restrict__ x,
                 const float* __restrict__ anchors,
                 const int* __restrict__ img_dim,
                 float* __restrict__ out)
{
    const int n = blockIdx.x * NT + threadIdx.x;   // point index: ((b*NA+a)*G+i)*G+j
    const int j   = n % G;
    const int r   = n / G;
    const int i   = r % G;
    const int pan = r / G;                         // b*NA + a
    const int a   = pan % NA;

    const float stride_f = (float)(*img_dim) / (float)G;   // 8
    const float aw = anchors[2 * a + 0];   // (anchor/stride)*stride cancels
    const float ah = anchors[2 * a + 1];

    // Strided reads (coalesced across the wave: consecutive n -> consecutive j),
    // contiguous writes (85 floats per thread). Transpose happens in registers.
    const float* __restrict__ bp = x + (size_t)pan * NC * GG + (size_t)i * G + j;
    float* __restrict__ op = out + (size_t)n * NC;

    const float v0 = bp[0 * (size_t)GG];
    const float v1 = bp[1 * (size_t)GG];
    const float v2 = bp[2 * (size_t)GG];
    const float v3 = bp[3 * (size_t)GG];
    const float v4 = bp[4 * (size_t)GG];

    op[0] = (sigmoidf(v0) + (float)j) * stride_f;  // bx*stride
    op[1] = (sigmoidf(v1) + (float)i) * stride_f;  // by*stride
    op[2] = __expf(v2) * aw;                       // bw*stride
    op[3] = __expf(v3) * ah;                       // bh*stride
    op[4] = sigmoidf(v4);                          // conf

    #pragma unroll 16
    for (int c = 5; c < NC; ++c) {
        op[c] = sigmoidf(bp[(size_t)c * GG]);      // 80 class scores
    }
}

} // namespace

extern "C" void kernel_launch(void* const* d_in, const int* in_sizes, int n_in,
                              void* d_out, int out_size, void* d_ws, size_t ws_size,
                              hipStream_t stream) {
    const float* x       = (const float*)d_in[0];
    const float* anchors = (const float*)d_in[1];
    const int*   img_dim = (const int*)d_in[2];
    float* outp = (float*)d_out;

    yolo_decode<<<NBLK, NT, 0, stream>>>(x, anchors, img_dim, outp);
}

// Round 7
// 36.972 us; speedup vs baseline: 1.7253x; 1.7253x over previous
//
#include <hip/hip_runtime.h>

namespace {

typedef float f32x4 __attribute__((ext_vector_type(4)));

constexpr int G      = 76;
constexpr int NA     = 3;
constexpr int NC     = 85;             // 5 + 80 channels per anchor
constexpr int GG     = G * G;          // 5776
constexpr int RPB    = 2;              // grid-rows per block
constexpr int JV     = G / 4;          // 19 float4 per row per channel
constexpr int CH_V4  = RPB * JV;       // 38 float4 per channel chunk
constexpr int TOT_V4 = NC * CH_V4;     // 3230 float4 per block
constexpr int ROWF   = NC * G;         // 6460 floats per output row-slab
constexpr int LDSF   = RPB * ROWF;     // 12920 floats = 51,680 B
constexpr int NT     = 512;
constexpr int NIT    = (TOT_V4 + NT - 1) / NT;   // 7

// LDS XOR swizzle at 16B-unit granularity: permutes units within each 128B
// group. Scalar writes (unit stride 85) spread across banks (~2-way, free);
// b128 reads of consecutive units stay conflict-free.
__device__ __forceinline__ int swz_word(int w) {
    const int U  = w >> 2;
    const int Us = U ^ ((U >> 3) & 7);
    return (Us << 2) | (w & 3);
}
__device__ __forceinline__ int swz_unit(int u) {
    return u ^ ((u >> 3) & 7);
}

__device__ __forceinline__ float sigmoidf(float v) {
    return __builtin_amdgcn_rcpf(1.0f + __expf(-v));
}

__global__ __launch_bounds__(NT)
void yolo_decode(const float* __restrict__ x,
                 const float* __restrict__ anchors,
                 const int* __restrict__ img_dim,
                 float* __restrict__ out)
{
    __shared__ alignas(16) float lds[LDSF];

    const int blk = blockIdx.x;
    const int ip  = blk % (G / RPB);            // 0..37
    const int a   = (blk / (G / RPB)) % NA;
    const int b   = blk / ((G / RPB) * NA);
    const int i0  = ip * RPB;

    const float stride_f = (float)(*img_dim) / (float)G;   // 8
    const float aw = anchors[2 * a + 0];   // (anchor/stride)*stride cancels
    const float ah = anchors[2 * a + 1];

    const float* __restrict__ xin =
        x + (size_t)(b * (NA * NC) + a * NC) * GG + (size_t)i0 * G;

    const int tid = threadIdx.x;

    // Phase A: issue ALL global loads first (max outstanding vmcnt).
    f32x4 v[NIT];
    int cmap[NIT], qmap[NIT];
    bool vmap[NIT];
    #pragma unroll
    for (int it = 0; it < NIT; ++it) {
        const int k4 = it * NT + tid;
        vmap[it] = (k4 < TOT_V4);
        cmap[it] = k4 / CH_V4;
        qmap[it] = k4 - cmap[it] * CH_V4;       // 0..37: contiguous 608B chunk
        if (vmap[it])
            v[it] = *reinterpret_cast<const f32x4*>(
                xin + (size_t)cmap[it] * GG + (size_t)qmap[it] * 4);
    }

    // Phase B: transform + transpose-scatter into swizzled LDS as [r][j][c].
    #pragma unroll
    for (int it = 0; it < NIT; ++it) {
        if (vmap[it]) {
            const int c  = cmap[it];
            const int r  = qmap[it] / JV;       // 0..1
            const int j4 = qmap[it] - r * JV;   // 0..18
            const int wbase = r * ROWF;
            const float fi = (float)(i0 + r);
            #pragma unroll
            for (int e = 0; e < 4; ++e) {
                const int j = j4 * 4 + e;
                const float val = v[it][e];
                float rr;
                if (c == 0)      rr = (sigmoidf(val) + (float)j) * stride_f;
                else if (c == 1) rr = (sigmoidf(val) + fi) * stride_f;
                else if (c == 2) rr = __expf(val) * aw;
                else if (c == 3) rr = __expf(val) * ah;
                else             rr = sigmoidf(val);
                lds[swz_word(wbase + j * NC + c)] = rr;
            }
        }
    }
    __syncthreads();

    // Phase C: contiguous global NT stores; LDS read address de-swizzled.
    float* __restrict__ outp =
        out + (size_t)((b * NA + a) * GG + i0 * G) * NC;
    f32x4* __restrict__ o4p = reinterpret_cast<f32x4*>(outp);
    const f32x4* __restrict__ l4 = reinterpret_cast<const f32x4*>(lds);
    #pragma unroll
    for (int it = 0; it < NIT; ++it) {
        const int o4 = it * NT + tid;
        if (it < NIT - 1 || o4 < TOT_V4)
            __builtin_nontemporal_store(l4[swz_unit(o4)], o4p + o4);
    }
}

} // namespace

extern "C" void kernel_launch(void* const* d_in, const int* in_sizes, int n_in,
                              void* d_out, int out_size, void* d_ws, size_t ws_size,
                              hipStream_t stream) {
    const float* x       = (const float*)d_in[0];
    const float* anchors = (const float*)d_in[1];
    const int*   img_dim = (const int*)d_in[2];
    float* outp = (float*)d_out;

    const int B = in_sizes[0] / (NA * NC * GG);       // 16
    const int nblocks = B * NA * (G / RPB);           // 1824
    yolo_decode<<<nblocks, NT, 0, stream>>>(x, anchors, img_dim, outp);
}

// Round 8
// 36.128 us; speedup vs baseline: 1.7656x; 1.0234x over previous
//
#include <hip/hip_runtime.h>

namespace {

typedef float f32x4 __attribute__((ext_vector_type(4)));

constexpr int G      = 76;
constexpr int NA     = 3;
constexpr int NC     = 85;             // 5 + 80 channels per anchor
constexpr int GG     = G * G;          // 5776
constexpr int RPB    = 4;              // grid-rows per block -> 1216B read chunk/channel
constexpr int JV     = G / 4;          // 19 float4 per row per channel
constexpr int CH_V4  = RPB * JV;       // 76 float4 per channel chunk (contiguous rows)
constexpr int TOT_V4 = NC * CH_V4;     // 6460 float4 per block
constexpr int ROWF   = NC * G;         // 6460 floats per output row-slab
constexpr int LDSF   = RPB * ROWF;     // 25,840 floats = 103,360 B (1 block/CU)
constexpr int NT     = 1024;
constexpr int NIT    = (TOT_V4 + NT - 1) / NT;   // 7 (last: tid < 316)

__device__ __forceinline__ float sigmoidf(float v) {
    return __builtin_amdgcn_rcpf(1.0f + __expf(-v));
}

__global__ __launch_bounds__(NT)
void yolo_decode(const float* __restrict__ x,
                 const float* __restrict__ anchors,
                 const int* __restrict__ img_dim,
                 float* __restrict__ out)
{
    __shared__ alignas(16) float lds[LDSF];

    const int blk = blockIdx.x;
    const int ip  = blk % (G / RPB);            // 0..18
    const int a   = (blk / (G / RPB)) % NA;
    const int b   = blk / ((G / RPB) * NA);
    const int i0  = ip * RPB;

    const float stride_f = (float)(*img_dim) / (float)G;   // 8
    const float aw = anchors[2 * a + 0];   // (anchor/stride)*stride cancels
    const float ah = anchors[2 * a + 1];

    const float* __restrict__ xin =
        x + (size_t)(b * (NA * NC) + a * NC) * GG + (size_t)i0 * G;

    const int tid = threadIdx.x;

    // Phase A: issue ALL global loads first (max outstanding vmcnt).
    // Per channel c: 76 consecutive float4 = rows i0..i0+3 contiguous (1216 B).
    f32x4 v[NIT];
    int cmap[NIT], qmap[NIT];
    bool vmap[NIT];
    #pragma unroll
    for (int it = 0; it < NIT; ++it) {
        const int k4 = it * NT + tid;
        vmap[it] = (k4 < TOT_V4);
        cmap[it] = k4 / CH_V4;
        qmap[it] = k4 - cmap[it] * CH_V4;       // 0..75
        if (vmap[it])
            v[it] = *reinterpret_cast<const f32x4*>(
                xin + (size_t)cmap[it] * GG + (size_t)qmap[it] * 4);
    }

    // Phase B: transform + transpose-scatter into LDS as [r][j][c].
    #pragma unroll
    for (int it = 0; it < NIT; ++it) {
        if (vmap[it]) {
            const int c  = cmap[it];
            const int r  = qmap[it] / JV;       // 0..3
            const int j4 = qmap[it] - r * JV;   // 0..18
            float* __restrict__ lrow = lds + r * ROWF;
            const float fi = (float)(i0 + r);
            #pragma unroll
            for (int e = 0; e < 4; ++e) {
                const int j = j4 * 4 + e;
                const float val = v[it][e];
                float rr;
                if (c == 0)      rr = (sigmoidf(val) + (float)j) * stride_f;
                else if (c == 1) rr = (sigmoidf(val) + fi) * stride_f;
                else if (c == 2) rr = __expf(val) * aw;
                else if (c == 3) rr = __expf(val) * ah;
                else             rr = sigmoidf(val);
                lrow[j * NC + c] = rr;
            }
        }
    }
    __syncthreads();

    // Phase C: 103,360 contiguous bytes per block, nontemporal float4 stores.
    float* __restrict__ outp =
        out + (size_t)((b * NA + a) * GG + i0 * G) * NC;
    const f32x4* __restrict__ l4 = reinterpret_cast<const f32x4*>(lds);
    f32x4* __restrict__ o4p = reinterpret_cast<f32x4*>(outp);
    #pragma unroll
    for (int it = 0; it < NIT; ++it) {
        const int o4 = it * NT + tid;
        if (it < NIT - 1 || o4 < TOT_V4)
            __builtin_nontemporal_store(l4[o4], o4p + o4);
    }
}

} // namespace

extern "C" void kernel_launch(void* const* d_in, const int* in_sizes, int n_in,
                              void* d_out, int out_size, void* d_ws, size_t ws_size,
                              hipStream_t stream) {
    const float* x       = (const float*)d_in[0];
    const float* anchors = (const float*)d_in[1];
    const int*   img_dim = (const int*)d_in[2];
    float* outp = (float*)d_out;

    const int B = in_sizes[0] / (NA * NC * GG);       // 16
    const int nblocks = B * NA * (G / RPB);           // 912
    yolo_decode<<<nblocks, NT, 0, stream>>>(x, anchors, img_dim, outp);
}